// Round 6
// baseline (316.552 us; speedup 1.0000x reference)
//
#include <hip/hip_runtime.h>

// Problem constants (fixed by the reference).
#define BATCH   128
#define RANK    64
#define HIDDEN  4096
#define NADPT   256

// Geometry: 128 threads/block (2 waves), each thread 1 float4 -> HCHUNK=512.
// grid = (128, 8) = 1024 blocks -> 4 blocks/CU for tail smoothing.
// (Round-5 crash: HCHUNK=512 with 256 threads covered 1024 floats -> OOB
// writes past d_out -> page fault. Geometry must satisfy threads*4 == HCHUNK.)
#define TPB     128
#define HCHUNK  (TPB * 4)   // 512

// Native clang vector type: __builtin_nontemporal_store rejects
// HIP_vector_type<float,4> but accepts ext_vector_type.
typedef float vfloat4 __attribute__((ext_vector_type(4)));

__global__ __launch_bounds__(TPB) void PaddedLoraB_59459527246474_kernel(
    const float* __restrict__ y,      // [BATCH, RANK] f32 (harness upcasts f16->f32)
    const int*   __restrict__ wids,   // [BATCH]
    const float* __restrict__ loraB,  // [NADPT, RANK, HIDDEN] f32
    float*       __restrict__ out)    // [BATCH, HIDDEN] f32
{
    const int b   = blockIdx.x;
    const int wid = wids[b] & (NADPT - 1);   // clamp: OOB insurance only
    const int h0  = blockIdx.y * HCHUNK + threadIdx.x * 4;   // max 4092 ✓

    // Stage 2*y[b,:] into LDS (fold the output scale here; exact in fp32).
    // All lanes read the same address per iteration -> broadcast, no conflicts.
    __shared__ float ysh[RANK];
    if (threadIdx.x < RANK) {
        ysh[threadIdx.x] = 2.0f * y[b * RANK + threadIdx.x];
    }
    __syncthreads();

    const float* Bp = loraB + (size_t)wid * (RANK * HIDDEN) + h0;

    float acc0 = 0.f, acc1 = 0.f, acc2 = 0.f, acc3 = 0.f;

#pragma unroll 8
    for (int r = 0; r < RANK; ++r) {
        const float4 v = *(const float4*)(Bp + (size_t)r * HIDDEN);  // 16B/lane coalesced
        const float yv = ysh[r];
        acc0 = fmaf(yv, v.x, acc0);
        acc1 = fmaf(yv, v.y, acc1);
        acc2 = fmaf(yv, v.z, acc2);
        acc3 = fmaf(yv, v.w, acc3);
    }

    // Write-once output: nontemporal 16B store, don't pollute L2.
    vfloat4 o;
    o.x = acc0; o.y = acc1; o.z = acc2; o.w = acc3;
    __builtin_nontemporal_store(o, (vfloat4*)(out + (size_t)b * HIDDEN + h0));
}

extern "C" void kernel_launch(void* const* d_in, const int* in_sizes, int n_in,
                              void* d_out, int out_size, void* d_ws, size_t ws_size,
                              hipStream_t stream) {
    // Bind inputs by element count (distinct sizes): y=8192, wids=128,
    // lora_B=67108864. Reference f16 tensors arrive as f32 (harness decode
    // paths are bf16/f32/int32 only; bf16-bits interpretation gave 2.2e19).
    const float* y     = nullptr;
    const int*   wids  = nullptr;
    const float* loraB = nullptr;
    for (int i = 0; i < n_in; ++i) {
        if (in_sizes[i] == BATCH * RANK)               y     = (const float*)d_in[i];
        else if (in_sizes[i] == BATCH)                 wids  = (const int*)d_in[i];
        else if (in_sizes[i] == NADPT * RANK * HIDDEN) loraB = (const float*)d_in[i];
    }
    float* out = (float*)d_out;  // [128,1,4096] f32

    dim3 grid(BATCH, HIDDEN / HCHUNK, 1);  // (128, 8) = 1024 blocks
    dim3 block(TPB, 1, 1);
    PaddedLoraB_59459527246474_kernel<<<grid, block, 0, stream>>>(y, wids, loraB, out);
}